// Round 8
// baseline (81.594 us; speedup 1.0000x reference)
//
#include <hip/hip_runtime.h>
#include <stdint.h>

// GGML Q8_0 fused dequant + GEMM:  out[16][8192] = x[16][8192] . W^T + bias
// HARNESS: quantized_weight arrives as int32, one GGML byte per element
// (zero-extended): 71,303,168 elems = 285.2 MB -> HBM-bound, ~45.3 us floor.
//
// R8 = R5 round structure, 2x the independent blocks per CU:
//   8 out-cols per block, 256 thr (4 waves), grid 1024 = exactly 4 blocks/CU
//   -> 4 decorrelated barrier groups per CU (R5 had 2; R6/R7 showed
//   vmcnt-counting and longer runs both regress, pointing at correlated
//   post-barrier issue gaps as the remaining limiter).
//   Chunk = 8 Q8 blocks x 8 rows (1088-B runs, as R5). Wave wv consumes
//   chunk-local Q8 blocks {wv, wv+4}. B-frag lanes c>=8 duplicate col c-8
//   (broadcast LDS reads, free); out written from c<8.
// Primitives identical to verified R5: width-4 global_load_lds, 274-dword
// bank-balanced LDS row stride, perm/xor/pk_add dequant,
// mfma_f32_16x16x32_f16 + f32 scale fixup, LDS cross-wave reduce.

typedef _Float16 half8   __attribute__((ext_vector_type(8)));
typedef _Float16 half2v  __attribute__((ext_vector_type(2)));
typedef float    float4v __attribute__((ext_vector_type(4)));
typedef uint2    __attribute__((may_alias)) u2a;
typedef float4v  __attribute__((may_alias)) f4a;

#define RSTRIDE_DW 274u     // LDS dwords per row image (272 data + 2 pad)
#define RSTRIDE_B  1096u
#define CHUNK_DW   272u     // global dwords per row per chunk (8 Q8 blocks)
#define NSLOT      9        // staging slots per wave (s = wv+4t, t=0..8)
#define BUFBYTES   8960u    // 35 slots * 256 B (span 7*274+272 = 2190 dw)

// two zero-extended quant bytes (.b0 of lo,hi) -> packed f16 pair == exact q
__device__ __forceinline__ uint32_t qpair(uint32_t lo, uint32_t hi) {
  uint32_t r = __builtin_amdgcn_perm(hi, lo, 0x0C040C00u); // [lo.b0,0,hi.b0,0]
  r ^= 0x64806480u;                                        // f16 1152+q each
  half2v v = __builtin_bit_cast(half2v, r);
  v = v + __builtin_bit_cast(half2v, (uint32_t)0xE480E480u); // -1152,-1152
  return __builtin_bit_cast(uint32_t, v);
}

__device__ __forceinline__ void gload4(const int* g, unsigned char* l) {
  __builtin_amdgcn_global_load_lds(
      (__attribute__((address_space(1))) void*)(void*)(const_cast<int*>(g)),
      (__attribute__((address_space(3))) void*)(void*)l,
      4, 0, 0);
}

extern "C" __global__ __launch_bounds__(256, 4)
void q8lin_kernel(const float* __restrict__ x,
                  const int* __restrict__ wq,
                  const float* __restrict__ bias,
                  float* __restrict__ out)
{
  __shared__ __align__(16) unsigned char lds[2][BUFBYTES]; // 17.5 KB
  __shared__ __align__(16) float red[4][8][16];            // 2 KB

  const int tid  = threadIdx.x;
  const int wv   = tid >> 6;    // wave index (4 waves)
  const int lane = tid & 63;
  const int c    = lane & 15;   // batch row (A side); col index mod dup (B)
  const int c8   = c & 7;       // real output col within block
  const int ksub = lane >> 4;   // k-subgroup within MFMA
  const int g    = blockIdx.x;  // output cols [g*8, g*8+8)

  // staging map: slot s = min(wv + 4t, 34); flat dword f = s*64+lane;
  // row r = f/274 (clamp 7), in-row dword u = f-274r (clamp 271).
  unsigned gofs[NSLOT], lofs[NSLOT];
#pragma unroll
  for (int t = 0; t < NSLOT; ++t) {
    unsigned s = (unsigned)(wv + 4 * t); if (s > 34u) s = 34u;
    unsigned f = s * 64u + (unsigned)lane;
    unsigned r = f / RSTRIDE_DW; if (r > 7u) r = 7u;
    unsigned u = f - r * RSTRIDE_DW; if (u > 271u) u = 271u;
    gofs[t] = r * 8704u + u;   // dword offset within block's 8-row panel
    lofs[t] = s * 256u;        // uniform LDS slot base (builtin adds lane*4)
  }
  const int* panel = wq + (size_t)g * (8u * 8704u);

  const int      j1  = wv, j2 = wv + 4;          // chunk-local Q8 blocks
  const unsigned rb1 = RSTRIDE_B * (unsigned)c8 + 136u * (unsigned)j1;
  const unsigned rb2 = RSTRIDE_B * (unsigned)c8 + 136u * (unsigned)j2;
  const float*   xrow = x + (size_t)c * 8192 + (unsigned)ksub * 8u;

  float4v acc = {0.f, 0.f, 0.f, 0.f};

  // prologue: chunk 0
#pragma unroll
  for (int t = 0; t < NSLOT; ++t) gload4(panel + gofs[t], &lds[0][0] + lofs[t]);
  __syncthreads();

#pragma unroll 1
  for (int q = 0; q < 32; ++q) {
    if (q < 31) {
      unsigned char* nb  = &lds[(q + 1) & 1][0];
      const int*     src = panel + (unsigned)(q + 1) * CHUNK_DW;
#pragma unroll
      for (int t = 0; t < NSLOT; ++t) gload4(src + gofs[t], nb + lofs[t]);
    }
    const unsigned char* cur = &lds[q & 1][0];

#pragma unroll
    for (int jj = 0; jj < 2; ++jj) {
      const unsigned rb = jj ? rb2 : rb1;
      const int      j  = jj ? j2 : j1;

      // fp16 scale from zero-extended dwords 0,1 of (row c8, block j)
      u2a s01 = *(const u2a*)(cur + rb);
      uint32_t sv = __builtin_amdgcn_perm(s01.y, s01.x, 0x0C0C0400u);
      const float dsc = (float)__builtin_bit_cast(_Float16, (uint16_t)sv);

      // 8 quants for this lane: dwords 2+8*ksub.. (8-B aligned b64 reads;
      // lanes c and c+8 share addresses -> broadcast, conflict-free)
      const unsigned qb = rb + 8u + 32u * (unsigned)ksub;
      u2a d0 = *(const u2a*)(cur + qb);
      u2a d1 = *(const u2a*)(cur + qb + 8);
      u2a d2 = *(const u2a*)(cur + qb + 16);
      u2a d3 = *(const u2a*)(cur + qb + 24);
      half8 bfrag;
      { union { half8 h; uint32_t u[4]; } ub;
        ub.u[0] = qpair(d0.x, d0.y);
        ub.u[1] = qpair(d1.x, d1.y);
        ub.u[2] = qpair(d2.x, d2.y);
        ub.u[3] = qpair(d3.x, d3.y);
        bfrag = ub.h; }

      // A fragment: x[c][q*256 + j*32 + ksub*8 ..+8) as f16 RTZ (L2-resident)
      const float* xp = xrow + (size_t)q * 256 + (unsigned)j * 32u;
      float4v f0 = *(const f4a*)xp;
      float4v f1 = *(const f4a*)(xp + 4);
      half8 afrag;
      { union { half8 h; uint32_t u[4]; } ua;
        ua.u[0] = __builtin_bit_cast(uint32_t, __builtin_amdgcn_cvt_pkrtz(f0[0], f0[1]));
        ua.u[1] = __builtin_bit_cast(uint32_t, __builtin_amdgcn_cvt_pkrtz(f0[2], f0[3]));
        ua.u[2] = __builtin_bit_cast(uint32_t, __builtin_amdgcn_cvt_pkrtz(f1[0], f1[1]));
        ua.u[3] = __builtin_bit_cast(uint32_t, __builtin_amdgcn_cvt_pkrtz(f1[2], f1[3]));
        afrag = ua.h; }

      float4v D = __builtin_amdgcn_mfma_f32_16x16x32_f16(
          afrag, bfrag, (float4v){0.f, 0.f, 0.f, 0.f}, 0, 0, 0);
      acc[0] = fmaf(dsc, D[0], acc[0]);
      acc[1] = fmaf(dsc, D[1], acc[1]);
      acc[2] = fmaf(dsc, D[2], acc[2]);
      acc[3] = fmaf(dsc, D[3], acc[3]);
    }

    __syncthreads();  // next buffer staged; cur free for overwrite
  }

  // cross-wave K-reduction. C/D layout (m89): col=lane&15, row=(lane>>4)*4+r
  if (c < 8) *(f4a*)(&red[wv][c][ksub * 4]) = acc;
  __syncthreads();

  if (tid < 128) {
    const int cc = tid & 7;
    const int rr = tid >> 3;
    float s = bias[g * 8 + cc];
#pragma unroll
    for (int w = 0; w < 4; ++w) s += red[w][cc][rr];
    out[(size_t)rr * 8192 + (size_t)(g * 8 + cc)] = s;
  }
}

extern "C" void kernel_launch(void* const* d_in, const int* in_sizes, int n_in,
                              void* d_out, int out_size, void* d_ws, size_t ws_size,
                              hipStream_t stream) {
  const float* x    = (const float*)d_in[0];
  const int*   wq   = (const int*)d_in[1];
  const float* bias = (const float*)d_in[2];
  float*       out  = (float*)d_out;
  (void)in_sizes; (void)n_in; (void)d_ws; (void)ws_size; (void)out_size;
  q8lin_kernel<<<dim3(8192 / 8), dim3(256), 0, stream>>>(x, wq, bias, out);
}

// Round 9
// 61.659 us; speedup vs baseline: 1.3233x; 1.3233x over previous
//
#include <hip/hip_runtime.h>
#include <stdint.h>

// GGML Q8_0 fused dequant + GEMM:  out[16][8192] = x[16][8192] . W^T + bias
// HARNESS: quantized_weight arrives as int32, one GGML byte per element
// (zero-extended): 71,303,168 elems = 285.2 MB -> HBM-bound, ~45.3 us floor.
//
// R9 = R5 + counted-vmcnt depth-2 pipeline with ASM-ISOLATED LDS reads.
//   R5's round serially pays ~900cy HBM latency: syncthreads drains vmcnt(0)
//   for loads issued ~200cy earlier. R6's counted fix regressed, likely via
//   compiler-inserted conservative vmcnt(0) between global_load_lds and the
//   (compiler-visible) ds_reads. Here fragment reads are inline asm: the only
//   ordering is my `s_waitcnt vmcnt(9)` + raw s_barrier (chunk q+2's 9 loads
//   stay in flight across the barrier), volatile-asm order keeps reads after
//   the barrier, and rule-18 lgkmcnt(0)+sched_barrier(0) guards the uses.
//   Triple-buffered LDS (3x18432B + 8KB red = 62 KB static, 2 blocks/CU).
// Primitives identical to verified R5: width-4 global_load_lds, 274-dword
// bank-balanced LDS row stride, perm/xor/pk_add dequant,
// mfma_f32_16x16x32_f16 + f32 scale fixup, LDS cross-wave reduce.

typedef _Float16 half8   __attribute__((ext_vector_type(8)));
typedef _Float16 half2v  __attribute__((ext_vector_type(2)));
typedef float    float4v __attribute__((ext_vector_type(4)));
typedef uint32_t u32x2   __attribute__((ext_vector_type(2)));
typedef float4v  __attribute__((may_alias)) f4a;

// two zero-extended quant bytes (.b0 of lo,hi) -> packed f16 pair == exact q
__device__ __forceinline__ uint32_t qpair(uint32_t lo, uint32_t hi) {
  uint32_t r = __builtin_amdgcn_perm(hi, lo, 0x0C040C00u); // [lo.b0,0,hi.b0,0]
  r ^= 0x64806480u;                                        // f16 1152+q each
  half2v v = __builtin_bit_cast(half2v, r);
  v = v + __builtin_bit_cast(half2v, (uint32_t)0xE480E480u); // -1152,-1152
  return __builtin_bit_cast(uint32_t, v);
}

__device__ __forceinline__ void gload4(const int* g, unsigned char* l) {
  __builtin_amdgcn_global_load_lds(
      (__attribute__((address_space(1))) void*)(void*)(const_cast<int*>(g)),
      (__attribute__((address_space(3))) void*)(void*)l,
      4, 0, 0);
}

__device__ __forceinline__ uint32_t lds_off(const void* p) {
  return (uint32_t)(uintptr_t)(__attribute__((address_space(3))) const void*)p;
}

// asm ds_read_b64: compiler sees no LDS access -> no conservative vmcnt(0).
__device__ __forceinline__ u32x2 ds_read64(uint32_t addr) {
  u32x2 d;
  asm volatile("ds_read_b64 %0, %1" : "=v"(d) : "v"(addr));
  return d;
}

extern "C" __global__ __launch_bounds__(512, 4)
void q8lin_kernel(const float* __restrict__ x,
                  const int* __restrict__ wq,
                  const float* __restrict__ bias,
                  float* __restrict__ out)
{
  __shared__ __align__(16) unsigned char lds[3][18432]; // 54 KB, triple buffer
  __shared__ __align__(16) float red[8][16][16];        // 8 KB

  const int tid  = threadIdx.x;
  const int wv   = tid >> 6;    // wave = chunk-local Q8 block index
  const int lane = tid & 63;
  const int c    = lane & 15;   // batch row (A) and weight row / out col (B)
  const int ksub = lane >> 4;   // k-subgroup within MFMA
  const int g    = blockIdx.x;  // output cols [g*16, g*16+16)

  // staging map (R5-identical): slot s = wv+8t; flat dword f = s*64+lane;
  // row r = f/274 (clamp 15), in-row dword u = f-274r (clamp 271).
  const int* gptr[9];
  unsigned   lofs[9];
#pragma unroll
  for (int t = 0; t < 9; ++t) {
    unsigned s = (unsigned)(wv + 8 * t);
    unsigned f = s * 64u + (unsigned)lane;
    unsigned r = f / 274u; if (r > 15u) r = 15u;
    unsigned u = f - r * 274u; if (u > 271u) u = 271u;
    gptr[t] = wq + (size_t)((unsigned)g * 16u + r) * 8704u + u;
    lofs[t] = s * 256u;
  }

  const float*   xrow = x + (size_t)c * 8192 + (unsigned)wv * 32u
                          + (unsigned)ksub * 8u;
  const unsigned rb = (unsigned)c * 1096u + 136u * (unsigned)wv; // in-buffer
  const unsigned qb = rb + 8u + 32u * (unsigned)ksub;

  const uint32_t base0 = lds_off(&lds[0][0]);
  uint32_t baseA = base0;            // chunk q   (consume)
  uint32_t baseB = base0 + 18432u;   // chunk q+1 (complete by next barrier)
  uint32_t baseC = base0 + 36864u;   // chunk q+2 (landing)

  float4v acc = {0.f, 0.f, 0.f, 0.f};

  // prologue: chunks 0,1 in flight; drain chunk 0, keep chunk 1's 9 in flight
#pragma unroll
  for (int t = 0; t < 9; ++t) gload4(gptr[t], &lds[0][0] + lofs[t]);
#pragma unroll
  for (int t = 0; t < 9; ++t) gload4(gptr[t] + 272, &lds[1][0] + lofs[t]);
  asm volatile("s_waitcnt vmcnt(9)" ::: "memory");
  __builtin_amdgcn_s_barrier();

#pragma unroll 1
  for (int q = 0; q < 32; ++q) {
    // x loads first in the VMEM FIFO: compiler's own counted wait for them
    // drains chunk q+1's loads (needed next round) but not chunk q+2's.
    const float* xp = xrow + (size_t)q * 256;
    float4v f0 = *(const f4a*)xp;
    float4v f1 = *(const f4a*)(xp + 4);

    if (q < 30) {
      // stage chunk q+2 into the landing buffer (bufC)
      unsigned char* nb  = (unsigned char*)&lds[0][0] + (baseC - base0);
      const int      adv = (q + 2) * 272;
#pragma unroll
      for (int t = 0; t < 9; ++t) gload4(gptr[t] + adv, nb + lofs[t]);
    }

    // fragment reads from bufA via asm (invisible to compiler's LDS model)
    u32x2 s01 = ds_read64(baseA + rb);
    u32x2 d0  = ds_read64(baseA + qb);
    u32x2 d1  = ds_read64(baseA + qb + 8);
    u32x2 d2  = ds_read64(baseA + qb + 16);
    u32x2 d3  = ds_read64(baseA + qb + 24);
    asm volatile("s_waitcnt lgkmcnt(0)" ::: "memory");
    __builtin_amdgcn_sched_barrier(0);   // rule 18: pin uses after the wait

    uint32_t sv = __builtin_amdgcn_perm(s01[1], s01[0], 0x0C0C0400u);
    const float dsc = (float)__builtin_bit_cast(_Float16, (uint16_t)sv);

    half8 bfrag;
    { union { half8 h; uint32_t u[4]; } ub;
      ub.u[0] = qpair(d0[0], d0[1]);
      ub.u[1] = qpair(d1[0], d1[1]);
      ub.u[2] = qpair(d2[0], d2[1]);
      ub.u[3] = qpair(d3[0], d3[1]);
      bfrag = ub.h; }

    half8 afrag;
    { union { half8 h; uint32_t u[4]; } ua;
      ua.u[0] = __builtin_bit_cast(uint32_t, __builtin_amdgcn_cvt_pkrtz(f0[0], f0[1]));
      ua.u[1] = __builtin_bit_cast(uint32_t, __builtin_amdgcn_cvt_pkrtz(f0[2], f0[3]));
      ua.u[2] = __builtin_bit_cast(uint32_t, __builtin_amdgcn_cvt_pkrtz(f1[0], f1[1]));
      ua.u[3] = __builtin_bit_cast(uint32_t, __builtin_amdgcn_cvt_pkrtz(f1[2], f1[3]));
      afrag = ua.h; }

    float4v D = __builtin_amdgcn_mfma_f32_16x16x32_f16(
        afrag, bfrag, (float4v){0.f, 0.f, 0.f, 0.f}, 0, 0, 0);
    acc[0] = fmaf(dsc, D[0], acc[0]);
    acc[1] = fmaf(dsc, D[1], acc[1]);
    acc[2] = fmaf(dsc, D[2], acc[2]);
    acc[3] = fmaf(dsc, D[3], acc[3]);

    // end-of-round barrier: keep chunk q+2's loads in flight (main loop);
    // tail rounds drain fully so the last chunks are resident before reads.
    if (q < 30) {
      asm volatile("s_waitcnt vmcnt(9)" ::: "memory");
    } else {
      asm volatile("s_waitcnt vmcnt(0)" ::: "memory");
    }
    __builtin_amdgcn_s_barrier();

    uint32_t t0 = baseA; baseA = baseB; baseB = baseC; baseC = t0;
  }

  // cross-wave K-reduction. C/D layout (m89): col=lane&15, row=(lane>>4)*4+r
  *(f4a*)(&red[wv][c][ksub * 4]) = acc;
  __syncthreads();

  if (tid < 256) {
    const int cc = tid & 15;
    const int rr = tid >> 4;
    float s = bias[g * 16 + cc];
#pragma unroll
    for (int w = 0; w < 8; ++w) s += red[w][cc][rr];
    out[(size_t)rr * 8192 + (size_t)(g * 16 + cc)] = s;
  }
}

extern "C" void kernel_launch(void* const* d_in, const int* in_sizes, int n_in,
                              void* d_out, int out_size, void* d_ws, size_t ws_size,
                              hipStream_t stream) {
  const float* x    = (const float*)d_in[0];
  const int*   wq   = (const int*)d_in[1];
  const float* bias = (const float*)d_in[2];
  float*       out  = (float*)d_out;
  (void)in_sizes; (void)n_in; (void)d_ws; (void)ws_size; (void)out_size;
  q8lin_kernel<<<dim3(8192 / 16), dim3(512), 0, stream>>>(x, wq, bias, out);
}

// Round 10
// 53.739 us; speedup vs baseline: 1.5183x; 1.1474x over previous
//
#include <hip/hip_runtime.h>
#include <stdint.h>

// GGML Q8_0 fused dequant + GEMM:  out[16][8192] = x[16][8192] . W^T + bias
// HARNESS: quantized_weight arrives as int32, one GGML byte per element
// (zero-extended): 71,303,168 elems = 285.2 MB -> HBM-bound, ~45.3 us floor.
//
// R10 = R5 (best: 56.7 us; every restructuring attempt R6-R9 regressed)
//       + x pre-converted to f16 in a ~0.3us pre-pass (d_ws):
//   inner round drops from 2 x-loads + 4 cvt_pkrtz to ONE 16-B x-load and a
//   bit_cast A-fragment; halves x L2 traffic (256->128 MB device-wide).
//   Conversion uses the same cvt_pkrtz (RTZ) -> numerics bit-identical.
// Weight path identical to verified R5: width-4 global_load_lds staging
// (1088-B runs), 274-dword bank-balanced LDS row stride, double-buffered,
// one __syncthreads per chunk, perm/xor/pk_add dequant,
// mfma_f32_16x16x32_f16 + f32 scale fixup, LDS cross-wave reduce.

typedef _Float16 half8   __attribute__((ext_vector_type(8)));
typedef _Float16 half2v  __attribute__((ext_vector_type(2)));
typedef float    float4v __attribute__((ext_vector_type(4)));
typedef uint2    __attribute__((may_alias)) u2a;
typedef uint4    __attribute__((may_alias)) u4a;
typedef float4v  __attribute__((may_alias)) f4a;

// two zero-extended quant bytes (.b0 of lo,hi) -> packed f16 pair == exact q
__device__ __forceinline__ uint32_t qpair(uint32_t lo, uint32_t hi) {
  uint32_t r = __builtin_amdgcn_perm(hi, lo, 0x0C040C00u); // [lo.b0,0,hi.b0,0]
  r ^= 0x64806480u;                                        // f16 1152+q each
  half2v v = __builtin_bit_cast(half2v, r);
  v = v + __builtin_bit_cast(half2v, (uint32_t)0xE480E480u); // -1152,-1152
  return __builtin_bit_cast(uint32_t, v);
}

__device__ __forceinline__ void gload4(const int* g, unsigned char* l) {
  __builtin_amdgcn_global_load_lds(
      (__attribute__((address_space(1))) void*)(void*)(const_cast<int*>(g)),
      (__attribute__((address_space(3))) void*)(void*)l,
      4, 0, 0);
}

// pre-pass: x f32 -> f16 (RTZ, identical to the old inline cvt_pkrtz path)
extern "C" __global__ __launch_bounds__(256)
void xcvt_kernel(const float* __restrict__ x, _Float16* __restrict__ xh) {
  const int i = (blockIdx.x * 256 + threadIdx.x) * 8;   // 131072 elems total
  float4v f0 = *(const f4a*)(x + i);
  float4v f1 = *(const f4a*)(x + i + 4);
  uint4 o;
  o.x = __builtin_bit_cast(uint32_t, __builtin_amdgcn_cvt_pkrtz(f0[0], f0[1]));
  o.y = __builtin_bit_cast(uint32_t, __builtin_amdgcn_cvt_pkrtz(f0[2], f0[3]));
  o.z = __builtin_bit_cast(uint32_t, __builtin_amdgcn_cvt_pkrtz(f1[0], f1[1]));
  o.w = __builtin_bit_cast(uint32_t, __builtin_amdgcn_cvt_pkrtz(f1[2], f1[3]));
  *(u4a*)(xh + i) = o;
}

extern "C" __global__ __launch_bounds__(512, 4)
void q8lin_kernel(const _Float16* __restrict__ xh,
                  const int* __restrict__ wq,
                  const float* __restrict__ bias,
                  float* __restrict__ out)
{
  __shared__ __align__(16) unsigned char lds[2][18432];
  __shared__ __align__(16) float red[8][16][16];

  const int tid  = threadIdx.x;
  const int wv   = tid >> 6;    // wave = chunk-local Q8 block index
  const int lane = tid & 63;
  const int c    = lane & 15;   // batch row (A) and weight row / out col (B)
  const int ksub = lane >> 4;   // k-subgroup within MFMA
  const int g    = blockIdx.x;  // output cols [g*16, g*16+16)

  // staging map (R5-identical): slot s = wv+8t (t=0..8); flat dword f = s*64+lane;
  // row r = f/274 (clamp 15), in-row dword u = f-274r (clamp 271).
  const int* gptr[9];
  unsigned   lofs[9];
#pragma unroll
  for (int t = 0; t < 9; ++t) {
    unsigned s = (unsigned)(wv + 8 * t);
    unsigned f = s * 64u + (unsigned)lane;
    unsigned r = f / 274u; if (r > 15u) r = 15u;
    unsigned u = f - r * 274u; if (u > 271u) u = 271u;
    gptr[t] = wq + (size_t)((unsigned)g * 16u + r) * 8704u + u;
    lofs[t] = s * 256u;
  }

  const _Float16* xrow = xh + (size_t)c * 8192 + (unsigned)wv * 32u
                            + (unsigned)ksub * 8u;
  const unsigned rb = (unsigned)c * 1096u + 136u * (unsigned)wv;
  const unsigned qb = rb + 8u + 32u * (unsigned)ksub;

  float4v acc = {0.f, 0.f, 0.f, 0.f};

  // prologue: chunk 0
#pragma unroll
  for (int t = 0; t < 9; ++t) gload4(gptr[t], &lds[0][0] + lofs[t]);
  __syncthreads();

#pragma unroll 1
  for (int q = 0; q < 32; ++q) {
    const unsigned char* cur = &lds[q & 1][0];
    if (q < 31) {
      unsigned char* nxt = &lds[(q + 1) & 1][0];
      const int adv = (q + 1) * 272;
#pragma unroll
      for (int t = 0; t < 9; ++t) gload4(gptr[t] + adv, nxt + lofs[t]);
    }

    // scale: 2 int32 (bytes in .b0) at row byte 136*wv
    u2a s01 = *(const u2a*)(cur + rb);
    uint32_t sv = __builtin_amdgcn_perm(s01.y, s01.x, 0x0C0C0400u);
    const float dsc = (float)__builtin_bit_cast(_Float16, (uint16_t)sv);

    // quants: 8 int32 at row byte 136*wv + 8 + ksub*32 (bank-balanced b64s)
    u2a d0 = *(const u2a*)(cur + qb);
    u2a d1 = *(const u2a*)(cur + qb + 8);
    u2a d2 = *(const u2a*)(cur + qb + 16);
    u2a d3 = *(const u2a*)(cur + qb + 24);
    half8 bfrag;
    { union { half8 h; uint32_t u[4]; } ub;
      ub.u[0] = qpair(d0.x, d0.y);
      ub.u[1] = qpair(d1.x, d1.y);
      ub.u[2] = qpair(d2.x, d2.y);
      ub.u[3] = qpair(d3.x, d3.y);
      bfrag = ub.h; }

    // A fragment: one 16-B load of pre-converted f16 x (L2-resident)
    half8 afrag = *(const half8*)(xrow + (size_t)q * 256);

    float4v D = __builtin_amdgcn_mfma_f32_16x16x32_f16(
        afrag, bfrag, (float4v){0.f, 0.f, 0.f, 0.f}, 0, 0, 0);
    acc[0] = fmaf(dsc, D[0], acc[0]);
    acc[1] = fmaf(dsc, D[1], acc[1]);
    acc[2] = fmaf(dsc, D[2], acc[2]);
    acc[3] = fmaf(dsc, D[3], acc[3]);

    __syncthreads();  // next buffer staged; cur free for overwrite
  }

  // cross-wave K-reduction. C/D layout (m89): col=lane&15, row=(lane>>4)*4+r
  *(f4a*)(&red[wv][c][ksub * 4]) = acc;
  __syncthreads();

  if (tid < 256) {
    const int cc = tid & 15;
    const int rr = tid >> 4;
    float s = bias[g * 16 + cc];
#pragma unroll
    for (int w = 0; w < 8; ++w) s += red[w][cc][rr];
    out[(size_t)rr * 8192 + (size_t)(g * 16 + cc)] = s;
  }
}

extern "C" void kernel_launch(void* const* d_in, const int* in_sizes, int n_in,
                              void* d_out, int out_size, void* d_ws, size_t ws_size,
                              hipStream_t stream) {
  const float* x    = (const float*)d_in[0];
  const int*   wq   = (const int*)d_in[1];
  const float* bias = (const float*)d_in[2];
  float*       out  = (float*)d_out;
  _Float16*    xh   = (_Float16*)d_ws;    // 16*8192*2 B = 256 KiB scratch
  (void)in_sizes; (void)n_in; (void)ws_size; (void)out_size;
  // pre-pass: x -> f16 (RTZ), 131072 elems / (256 thr * 8) = 64 blocks
  xcvt_kernel<<<dim3(64), dim3(256), 0, stream>>>(x, xh);
  q8lin_kernel<<<dim3(8192 / 16), dim3(512), 0, stream>>>(xh, wq, bias, out);
}